// Round 1
// baseline (14.117 us; speedup 1.0000x reference)
//
#include <hip/hip_runtime.h>

// ANI radial symmetry function:
//   out[b,a,r] = sum_n exp(-eta[r]*(r_ij[b,a,n]-rss[r])^2) * cutoff(r_ij) * mask
//   cutoff(d) = 0.5*(cos(pi*d/3)+1) for d < 3 else 0
//
// Shapes: r_ij/mask [16,2048,96] f32, etas/rss [16] f32, out [16,2048,16] f32.
// Strategy: block=256 handles 16 rows. Stage r and w=cutoff*mask into padded
// LDS (stride 100 -> conflict-free broadcast reads). Thread (row=tid>>4,
// rIdx=tid&15) accumulates over the 96 neighbors with the RBF exponent as a
// Horner polynomial in the log2 domain (v_exp_f32 directly, log2e folded in).

#define NROWS 16   // rows per block
#define NN    96   // neighbors per row
#define RR    16   // radial basis count
#define LP    100  // padded LDS row stride in floats (100*4 B, 16B-aligned)

__global__ __launch_bounds__(256) void ani_radial_kernel(
    const float* __restrict__ r_ij,
    const float* __restrict__ mask,
    const float* __restrict__ etas,
    const float* __restrict__ rss,
    float* __restrict__ out)
{
    __shared__ float ls_r[NROWS * LP];
    __shared__ float ls_w[NROWS * LP];

    const int tid = threadIdx.x;
    const long long rowBase = (long long)blockIdx.x * NROWS;
    const float* __restrict__ src_r = r_ij + rowBase * NN;
    const float* __restrict__ src_m = mask + rowBase * NN;

    // ---- Phase 1: stage r and w = cutoff(r)*mask into padded LDS ----
    // 16 rows * 96 = 1536 floats = 384 float4 per array; 256 threads loop.
    const float PI_3 = 1.0471975511965976f;  // pi/3
    #pragma unroll
    for (int i = tid; i < (NROWS * NN) / 4; i += 256) {
        const int row = i / (NN / 4);
        const int nq  = i - row * (NN / 4);
        const float4 r4 = reinterpret_cast<const float4*>(src_r)[i];
        const float4 m4 = reinterpret_cast<const float4*>(src_m)[i];

        float rr[4] = {r4.x, r4.y, r4.z, r4.w};
        float mm[4] = {m4.x, m4.y, m4.z, m4.w};
        float ww[4];
        #pragma unroll
        for (int j = 0; j < 4; ++j) {
            float c = __cosf(rr[j] * PI_3);          // v_mul + v_cos
            float w = __builtin_fmaf(0.5f, c, 0.5f); // 0.5*(cos+1)
            ww[j] = (rr[j] < 3.0f) ? w * mm[j] : 0.0f;
        }

        const int lidx = row * LP + nq * 4;
        *reinterpret_cast<float4*>(&ls_r[lidx]) = r4;
        *reinterpret_cast<float4*>(&ls_w[lidx]) =
            make_float4(ww[0], ww[1], ww[2], ww[3]);
    }
    __syncthreads();

    // ---- Phase 2: per-thread accumulation over 96 neighbors ----
    const int rl   = tid >> 4;  // local row 0..15
    const int rIdx = tid & 15;  // radial index 0..15

    const float eta = etas[rIdx];
    const float rs  = rss[rIdx];
    const float LOG2E = 1.4426950408889634f;
    const float k  = -eta * LOG2E;        // exponent in log2 domain
    const float pb = -2.0f * k * rs;      // k*(d-rs)^2 = k*d^2 + pb*d + pc
    const float pc = k * rs * rs;

    const float* __restrict__ lr = &ls_r[rl * LP];
    const float* __restrict__ lw = &ls_w[rl * LP];

    float acc0 = 0.0f, acc1 = 0.0f, acc2 = 0.0f, acc3 = 0.0f;
    #pragma unroll 8
    for (int nq = 0; nq < NN / 4; ++nq) {
        const float4 r4 = *reinterpret_cast<const float4*>(&lr[nq * 4]);
        const float4 w4 = *reinterpret_cast<const float4*>(&lw[nq * 4]);
        acc0 = __builtin_fmaf(
            __builtin_amdgcn_exp2f(__builtin_fmaf(__builtin_fmaf(k, r4.x, pb), r4.x, pc)),
            w4.x, acc0);
        acc1 = __builtin_fmaf(
            __builtin_amdgcn_exp2f(__builtin_fmaf(__builtin_fmaf(k, r4.y, pb), r4.y, pc)),
            w4.y, acc1);
        acc2 = __builtin_fmaf(
            __builtin_amdgcn_exp2f(__builtin_fmaf(__builtin_fmaf(k, r4.z, pb), r4.z, pc)),
            w4.z, acc2);
        acc3 = __builtin_fmaf(
            __builtin_amdgcn_exp2f(__builtin_fmaf(__builtin_fmaf(k, r4.w, pb), r4.w, pc)),
            w4.w, acc3);
    }

    const float acc = (acc0 + acc1) + (acc2 + acc3);
    out[(rowBase + rl) * RR + rIdx] = acc;
}

extern "C" void kernel_launch(void* const* d_in, const int* in_sizes, int n_in,
                              void* d_out, int out_size, void* d_ws, size_t ws_size,
                              hipStream_t stream) {
    const float* r_ij = (const float*)d_in[0];
    const float* mask = (const float*)d_in[1];
    const float* etas = (const float*)d_in[2];
    const float* rss  = (const float*)d_in[3];
    float* out = (float*)d_out;

    const int totalRows = in_sizes[0] / NN;       // B*A = 32768
    const int grid = totalRows / NROWS;           // 2048 blocks

    ani_radial_kernel<<<grid, 256, 0, stream>>>(r_ij, mask, etas, rss, out);
}